// Round 1
// baseline (1723.492 us; speedup 1.0000x reference)
//
#include <hip/hip_runtime.h>
#include <hip/hip_fp16.h>
#include <cstdint>

// Problem constants
// B=64, T=512, F=1024, U=256, G=4U=1024
#define BB 64
#define TT 512
#define FF 1024
#define UU 256
#define GG 1024

typedef _Float16 half2v __attribute__((ext_vector_type(2)));

__device__ __forceinline__ float dot2f(uint32_t h, uint32_t w, float acc) {
#if __has_builtin(__builtin_amdgcn_fdot2)
  union U_ { uint32_t u; half2v v; };
  U_ H; H.u = h;
  U_ W; W.u = w;
  return __builtin_amdgcn_fdot2(H.v, W.v, acc, false);
#else
  __half2 hh = *reinterpret_cast<__half2*>(&h);
  __half2 ww = *reinterpret_cast<__half2*>(&w);
  float2 hf = __half22float2(hh), wf = __half22float2(ww);
  return fmaf(hf.y, wf.y, fmaf(hf.x, wf.x, acc));
#endif
}

__device__ __forceinline__ float sigmf_(float x) { return 1.f / (1.f + __expf(-x)); }
__device__ __forceinline__ float tanhf_(float x) { return 1.f - 2.f / (1.f + __expf(2.f * x)); }

__device__ __forceinline__ uint32_t packh2(float lo, float hi) {
  __half2 h = __floats2half2_rn(lo, hi);
  return *reinterpret_cast<uint32_t*>(&h);
}

// ---------------- mask kernel: mask[b,t] = any(x[b,t,:] != 0) ----------------
__global__ __launch_bounds__(256) void mask_kernel(const float* __restrict__ x,
                                                   float* __restrict__ maskF) {
  int row = blockIdx.x;           // 0..B*T-1
  int tid = threadIdx.x;          // 256 threads, 4 floats each
  const float4* xr = (const float4*)(x + (size_t)row * FF);
  float4 v = xr[tid];
  bool nz = (v.x != 0.f) || (v.y != 0.f) || (v.z != 0.f) || (v.w != 0.f);
  __shared__ int flag;
  if (tid == 0) flag = 0;
  __syncthreads();
  if (__any(nz)) {
    if ((tid & 63) == 0) atomicOr(&flag, 1);
  }
  __syncthreads();
  if (tid == 0) maskF[row] = flag ? 1.f : 0.f;
}

// ---------------- pack W_h (256x1024 f32) -> fp16 pairs [128][1024] ----------
__global__ __launch_bounds__(256) void pack_wh(const float* __restrict__ Wh,
                                               uint32_t* __restrict__ whPk) {
  int idx = blockIdx.x * 256 + threadIdx.x;  // 131072 = 128*1024
  int p = idx >> 10;
  int c = idx & 1023;
  float lo = Wh[(size_t)(2 * p) * GG + c];
  float hi = Wh[(size_t)(2 * p + 1) * GG + c];
  whPk[idx] = packh2(lo, hi);
}

// ---------------- GEMM1: z = relu(x @ W_fc + b_fc), out half ----------------
#define GBK 16
__global__ __launch_bounds__(256) void gemm_fc(const float* __restrict__ A,
                                               const float* __restrict__ Bm,
                                               const float* __restrict__ bias,
                                               __half* __restrict__ C) {
  const int N = UU, K = FF;
  __shared__ float As[GBK][64 + 1];
  __shared__ float Bs[GBK][64];
  int tid = threadIdx.x;
  int tx = tid & 15, ty = tid >> 4;
  int m0 = blockIdx.x * 64, n0 = blockIdx.y * 64;
  float acc[4][4] = {};
  for (int k0 = 0; k0 < K; k0 += GBK) {
#pragma unroll
    for (int i = 0; i < 4; ++i) {
      int m = (tid >> 4) + 16 * i;
      int kk = tid & 15;
      As[kk][m] = A[(size_t)(m0 + m) * K + k0 + kk];
    }
#pragma unroll
    for (int i = 0; i < 4; ++i) {
      int kk = (tid >> 6) + 4 * i;
      int n = tid & 63;
      Bs[kk][n] = Bm[(size_t)(k0 + kk) * N + n0 + n];
    }
    __syncthreads();
#pragma unroll
    for (int kk = 0; kk < GBK; ++kk) {
      float a[4], bv[4];
#pragma unroll
      for (int i = 0; i < 4; ++i) a[i] = As[kk][ty * 4 + i];
#pragma unroll
      for (int j = 0; j < 4; ++j) bv[j] = Bs[kk][tx * 4 + j];
#pragma unroll
      for (int i = 0; i < 4; ++i)
#pragma unroll
        for (int j = 0; j < 4; ++j) acc[i][j] = fmaf(a[i], bv[j], acc[i][j]);
    }
    __syncthreads();
  }
#pragma unroll
  for (int i = 0; i < 4; ++i) {
    int m = m0 + ty * 4 + i;
#pragma unroll
    for (int j = 0; j < 4; ++j) {
      int n = n0 + tx * 4 + j;
      float v = acc[i][j] + bias[n];
      v = fmaxf(v, 0.f);
      C[(size_t)m * N + n] = __float2half(v);
    }
  }
}

// ---------------- GEMM2: zx = z @ W_x + b_lstm, A half, out half -------------
__global__ __launch_bounds__(256) void gemm_zx(const __half* __restrict__ A,
                                               const float* __restrict__ Bm,
                                               const float* __restrict__ bias,
                                               __half* __restrict__ C) {
  const int N = GG, K = UU;
  __shared__ float As[GBK][64 + 1];
  __shared__ float Bs[GBK][64];
  int tid = threadIdx.x;
  int tx = tid & 15, ty = tid >> 4;
  int m0 = blockIdx.x * 64, n0 = blockIdx.y * 64;
  float acc[4][4] = {};
  for (int k0 = 0; k0 < K; k0 += GBK) {
#pragma unroll
    for (int i = 0; i < 4; ++i) {
      int m = (tid >> 4) + 16 * i;
      int kk = tid & 15;
      As[kk][m] = (float)A[(size_t)(m0 + m) * K + k0 + kk];
    }
#pragma unroll
    for (int i = 0; i < 4; ++i) {
      int kk = (tid >> 6) + 4 * i;
      int n = tid & 63;
      Bs[kk][n] = Bm[(size_t)(k0 + kk) * N + n0 + n];
    }
    __syncthreads();
#pragma unroll
    for (int kk = 0; kk < GBK; ++kk) {
      float a[4], bv[4];
#pragma unroll
      for (int i = 0; i < 4; ++i) a[i] = As[kk][ty * 4 + i];
#pragma unroll
      for (int j = 0; j < 4; ++j) bv[j] = Bs[kk][tx * 4 + j];
#pragma unroll
      for (int i = 0; i < 4; ++i)
#pragma unroll
        for (int j = 0; j < 4; ++j) acc[i][j] = fmaf(a[i], bv[j], acc[i][j]);
    }
    __syncthreads();
  }
#pragma unroll
  for (int i = 0; i < 4; ++i) {
    int m = m0 + ty * 4 + i;
#pragma unroll
    for (int j = 0; j < 4; ++j) {
      int n = n0 + tx * 4 + j;
      float v = acc[i][j] + bias[n];
      C[(size_t)m * N + n] = __float2half(v);
    }
  }
}

// ---------------- recurrence: one block per batch ----------------------------
// block = 512 threads (8 waves). Thread t owns gate columns t and t+512.
// W_h fp16 pairs: 112 pairs/col in VGPRs, 16 pairs/col in LDS.
#define RP 112
#define LP 16

__global__ __launch_bounds__(512, 2) void lstm_rec(
    const uint32_t* __restrict__ whPk,  // [128][1024] fp16-pairs
    const __half* __restrict__ zxh,     // [B*T][1024]
    const float* __restrict__ maskF,    // [B*T]
    const float* __restrict__ Wp,       // [256]
    const float* __restrict__ bp,       // [1]
    float* __restrict__ out)            // [B*T]
{
  __shared__ uint4 ldsW4[8 * 512];      // 64KB, [slot][thread] interleaved
  __shared__ float gbuf[GG];
  __shared__ float cst[UU];
  __shared__ float hf[UU];
  __shared__ __align__(16) uint32_t hpk[UU / 2];
  __shared__ float red[8];

  int b = blockIdx.x;
  int t = threadIdx.x;
  int c0 = t, c1 = t + 512;

  uint32_t wA[RP], wB[RP];
#pragma unroll
  for (int r = 0; r < RP; ++r) {
    wA[r] = whPk[r * GG + c0];
    wB[r] = whPk[r * GG + c1];
  }
  uint32_t* ldsWu = (uint32_t*)ldsW4;
#pragma unroll
  for (int q = 0; q < LP; ++q) {
    int p = RP + q;
    ldsWu[(((q >> 2)) * 512 + t) * 4 + (q & 3)] = whPk[p * GG + c0];
    ldsWu[(((q >> 2) + 4) * 512 + t) * 4 + (q & 3)] = whPk[p * GG + c1];
  }
  if (t < UU) { cst[t] = 0.f; hf[t] = 0.f; }
  if (t < UU / 2) hpk[t] = 0u;
  float wp = (t < UU) ? Wp[t] : 0.f;
  float bpv = bp[0];
  __syncthreads();

  const __half* zrow = zxh + (size_t)b * TT * GG;
  const float* mrow = maskF + b * TT;

  for (int step = 0; step < TT; ++step) {
    float zx0 = (float)zrow[(size_t)step * GG + c0];
    float zx1 = (float)zrow[(size_t)step * GG + c1];
    float m = mrow[step];
    float a0 = 0.f, a1 = 0.f, a2 = 0.f, a3 = 0.f;
    const uint4* hpk4 = (const uint4*)hpk;
#pragma unroll
    for (int p4 = 0; p4 < RP / 4; ++p4) {
      uint4 h4 = hpk4[p4];
      a0 = dot2f(h4.x, wA[4 * p4 + 0], a0);
      a1 = dot2f(h4.y, wA[4 * p4 + 1], a1);
      a0 = dot2f(h4.z, wA[4 * p4 + 2], a0);
      a1 = dot2f(h4.w, wA[4 * p4 + 3], a1);
      a2 = dot2f(h4.x, wB[4 * p4 + 0], a2);
      a3 = dot2f(h4.y, wB[4 * p4 + 1], a3);
      a2 = dot2f(h4.z, wB[4 * p4 + 2], a2);
      a3 = dot2f(h4.w, wB[4 * p4 + 3], a3);
    }
#pragma unroll
    for (int s = 0; s < LP / 4; ++s) {
      uint4 h4 = hpk4[RP / 4 + s];
      uint4 wa = ldsW4[s * 512 + t];
      uint4 wb = ldsW4[(s + 4) * 512 + t];
      a0 = dot2f(h4.x, wa.x, a0);
      a1 = dot2f(h4.y, wa.y, a1);
      a0 = dot2f(h4.z, wa.z, a0);
      a1 = dot2f(h4.w, wa.w, a1);
      a2 = dot2f(h4.x, wb.x, a2);
      a3 = dot2f(h4.y, wb.y, a3);
      a2 = dot2f(h4.z, wb.z, a2);
      a3 = dot2f(h4.w, wb.w, a3);
    }
    gbuf[c0] = a0 + a1 + zx0;
    gbuf[c1] = a2 + a3 + zx1;
    __syncthreads();

    if (t < UU) {
      float gi = gbuf[t];
      float gf = gbuf[t + UU];
      float gg = gbuf[t + 2 * UU];
      float go = gbuf[t + 3 * UU];
      float ig = sigmf_(gi);
      float fg = sigmf_(gf);
      float g_ = tanhf_(gg);
      float og = sigmf_(go);
      float cn = fg * cst[t] + ig * g_;
      float hn = og * tanhf_(cn);
      float ceff = (m > 0.5f) ? cn : cst[t];
      float heff = (m > 0.5f) ? hn : hf[t];
      cst[t] = ceff;
      hf[t] = heff;
      float pp = heff * wp;
#pragma unroll
      for (int off = 32; off > 0; off >>= 1) pp += __shfl_down(pp, off, 64);
      if ((t & 63) == 0) red[t >> 6] = pp;
    }
    __syncthreads();

    if (t < UU / 2) hpk[t] = packh2(hf[2 * t], hf[2 * t + 1]);
    if (t == 0) {
      float s = red[0] + red[1] + red[2] + red[3] + bpv;
      out[b * TT + step] = 1.f / (1.f + __expf(-s));
    }
    __syncthreads();
  }
}

extern "C" void kernel_launch(void* const* d_in, const int* in_sizes, int n_in,
                              void* d_out, int out_size, void* d_ws, size_t ws_size,
                              hipStream_t stream) {
  const float* x = (const float*)d_in[0];
  const float* Wfc = (const float*)d_in[1];
  const float* bfc = (const float*)d_in[2];
  const float* Wx = (const float*)d_in[3];
  const float* Wh = (const float*)d_in[4];
  const float* blstm = (const float*)d_in[5];
  const float* Wp = (const float*)d_in[6];
  const float* bp = (const float*)d_in[7];
  float* out = (float*)d_out;

  char* ws = (char*)d_ws;
  float* maskF = (float*)(ws);                                  // 131072 B
  __half* zh = (__half*)(ws + 131072);                          // 16.78 MB
  __half* zxh = (__half*)(ws + 131072 + 16777216);              // 67.1 MB
  uint32_t* whPk = (uint32_t*)(ws + 131072 + 16777216 + 67108864);  // 512 KB

  mask_kernel<<<BB * TT, 256, 0, stream>>>(x, maskF);
  pack_wh<<<512, 256, 0, stream>>>(Wh, whPk);
  gemm_fc<<<dim3((BB * TT) / 64, UU / 64), 256, 0, stream>>>(x, Wfc, bfc, zh);
  gemm_zx<<<dim3((BB * TT) / 64, GG / 64), 256, 0, stream>>>(zh, Wx, blstm, zxh);
  lstm_rec<<<BB, 512, 0, stream>>>(whPk, zxh, maskF, Wp, bp, out);
}

// Round 2
// 1466.108 us; speedup vs baseline: 1.1756x; 1.1756x over previous
//
#include <hip/hip_runtime.h>
#include <hip/hip_fp16.h>
#include <cstdint>

// B=64, T=512, F=1024, U=256, G=4U=1024
#define BB 64
#define TT 512
#define FF 1024
#define UU 256
#define GG 1024

typedef _Float16 f16x8 __attribute__((ext_vector_type(8)));
typedef _Float16 half2v __attribute__((ext_vector_type(2)));
typedef float f32x4 __attribute__((ext_vector_type(4)));

__device__ __forceinline__ float dot2f(uint32_t h, uint32_t w, float acc) {
  union U_ { uint32_t u; half2v v; };
  U_ H; H.u = h;
  U_ W; W.u = w;
  return __builtin_amdgcn_fdot2(H.v, W.v, acc, false);
}

__device__ __forceinline__ float sigmf_(float x) { return 1.f / (1.f + __expf(-x)); }
__device__ __forceinline__ float tanhf_(float x) { return 1.f - 2.f / (1.f + __expf(2.f * x)); }

__device__ __forceinline__ uint32_t packh2(float lo, float hi) {
  __half2 h = __floats2half2_rn(lo, hi);
  return *reinterpret_cast<uint32_t*>(&h);
}

// ---------------- mask kernel: mask[b,t] = any(x[b,t,:] != 0) ----------------
__global__ __launch_bounds__(256) void mask_kernel(const float* __restrict__ x,
                                                   float* __restrict__ maskF) {
  int row = blockIdx.x;
  int tid = threadIdx.x;
  const float4* xr = (const float4*)(x + (size_t)row * FF);
  float4 v = xr[tid];
  bool nz = (v.x != 0.f) || (v.y != 0.f) || (v.z != 0.f) || (v.w != 0.f);
  __shared__ int flag;
  if (tid == 0) flag = 0;
  __syncthreads();
  if (__any(nz)) {
    if ((tid & 63) == 0) atomicOr(&flag, 1);
  }
  __syncthreads();
  if (tid == 0) maskF[row] = flag ? 1.f : 0.f;
}

// ---------------- pack W_h (256x1024 f32) -> fp16 pairs [128][1024] ----------
__global__ __launch_bounds__(256) void pack_wh(const float* __restrict__ Wh,
                                               uint32_t* __restrict__ whPk) {
  int idx = blockIdx.x * 256 + threadIdx.x;  // 131072 = 128*1024
  int p = idx >> 10;
  int c = idx & 1023;
  float lo = Wh[(size_t)(2 * p) * GG + c];
  float hi = Wh[(size_t)(2 * p + 1) * GG + c];
  whPk[idx] = packh2(lo, hi);
}

// ---------------- MFMA GEMM: C(f16) = [relu](A @ B + bias) -------------------
// A: M x K (row-major, TA = float or __half), B: K x N (row-major f32)
// tile 128(M) x 64(N), BK=32, 256 threads = 4 waves (2x2 wave grid)
template <typename TA, bool RELU>
__global__ __launch_bounds__(256) void gemm16(const TA* __restrict__ A,
                                              const float* __restrict__ Bm,
                                              const float* __restrict__ bias,
                                              __half* __restrict__ C,
                                              int M, int N, int K) {
  __shared__ _Float16 As[128][40];  // padded stride 80B (16B-aligned rows)
  __shared__ _Float16 Bs[64][40];   // transposed: Bs[n][k]
  int tid = threadIdx.x;
  int lane = tid & 63, w = tid >> 6;
  int wm = w & 1, wn = w >> 1;
  int m0 = blockIdx.x * 128, n0 = blockIdx.y * 64;
  int fr = lane & 15, ks = lane >> 4;

  f32x4 acc[4][2];
#pragma unroll
  for (int i = 0; i < 4; ++i)
#pragma unroll
    for (int j = 0; j < 2; ++j) acc[i][j] = (f32x4){0.f, 0.f, 0.f, 0.f};

  for (int k0 = 0; k0 < K; k0 += 32) {
    // stage A: 128 rows x 32 k -> f16
    {
      int r = tid >> 3, kq = (tid & 7) * 4;
#pragma unroll
      for (int i = 0; i < 4; ++i) {
        int row = r + 32 * i;
        const TA* src = A + (size_t)(m0 + row) * K + k0 + kq;
        if constexpr (sizeof(TA) == 4) {
          float4 v = *reinterpret_cast<const float4*>(src);
          union { uint2 u; _Float16 h[4]; } pk;
          pk.h[0] = (_Float16)v.x; pk.h[1] = (_Float16)v.y;
          pk.h[2] = (_Float16)v.z; pk.h[3] = (_Float16)v.w;
          *reinterpret_cast<uint2*>(&As[row][kq]) = pk.u;
        } else {
          uint2 v = *reinterpret_cast<const uint2*>(src);
          *reinterpret_cast<uint2*>(&As[row][kq]) = v;
        }
      }
      // stage B transposed: 32 k x 64 n
      int nn = tid & 63, kb = tid >> 6;
#pragma unroll
      for (int i = 0; i < 8; ++i) {
        int kk = kb + 4 * i;
        Bs[nn][kk] = (_Float16)Bm[(size_t)(k0 + kk) * N + n0 + nn];
      }
    }
    __syncthreads();
    f16x8 af[4], bf[2];
#pragma unroll
    for (int fm = 0; fm < 4; ++fm)
      af[fm] = *reinterpret_cast<const f16x8*>(&As[wm * 64 + fm * 16 + fr][ks * 8]);
#pragma unroll
    for (int fn = 0; fn < 2; ++fn)
      bf[fn] = *reinterpret_cast<const f16x8*>(&Bs[wn * 32 + fn * 16 + fr][ks * 8]);
#pragma unroll
    for (int fm = 0; fm < 4; ++fm)
#pragma unroll
      for (int fn = 0; fn < 2; ++fn)
        acc[fm][fn] = __builtin_amdgcn_mfma_f32_16x16x32_f16(af[fm], bf[fn], acc[fm][fn], 0, 0, 0);
    __syncthreads();
  }
  // epilogue: C/D layout col=lane&15, row=(lane>>4)*4+r  (m89-verified)
#pragma unroll
  for (int fm = 0; fm < 4; ++fm)
#pragma unroll
    for (int fn = 0; fn < 2; ++fn) {
      int mg0 = m0 + wm * 64 + fm * 16 + ks * 4;
      int ng = n0 + wn * 32 + fn * 16 + fr;
      float bv = bias[ng];
#pragma unroll
      for (int r = 0; r < 4; ++r) {
        float v = acc[fm][fn][r] + bv;
        if constexpr (RELU) v = fmaxf(v, 0.f);
        C[(size_t)(mg0 + r) * N + ng] = __float2half(v);
      }
    }
}

// ---------------- recurrence: one block per batch ----------------------------
// 512 threads (8 waves, 1 block/CU). Thread t owns gate columns t and t+512.
// Per column: 96 fp16-pairs in VGPRs, 32 pairs in LDS.
#define RP 96
#define LP 32

__global__ void __launch_bounds__(512) __attribute__((amdgpu_waves_per_eu(2)))
lstm_rec(const uint32_t* __restrict__ whPk,  // [128][1024] fp16-pairs
         const __half* __restrict__ zxh,     // [B*T][1024]
         const float* __restrict__ maskF,    // [B*T]
         const float* __restrict__ Wp,       // [256]
         const float* __restrict__ bp,       // [1]
         float* __restrict__ out)            // [B*T]
{
  __shared__ uint4 ldsW4[16 * 512];            // 128KB  [slot][thread]
  __shared__ float gbuf[GG];                   // 4KB
  __shared__ __align__(16) uint32_t hpk[UU / 2];  // 512B
  __shared__ float red[4];

  int b = blockIdx.x;
  int t = threadIdx.x;
  int c0 = t, c1 = t + 512;

  uint32_t wA[RP], wB[RP];
#pragma unroll
  for (int r = 0; r < RP; ++r) {
    wA[r] = whPk[r * GG + c0];
    wB[r] = whPk[r * GG + c1];
  }
  uint32_t* ldsWu = (uint32_t*)ldsW4;
#pragma unroll
  for (int q = 0; q < LP; ++q) {   // pairs RP..127
    int s = q >> 2, j = q & 3;
    ldsWu[((s)*512 + t) * 4 + j] = whPk[(RP + q) * GG + c0];
    ldsWu[((s + 8) * 512 + t) * 4 + j] = whPk[(RP + q) * GG + c1];
  }
  if (t < UU / 2) hpk[t] = 0u;
  float c_state = 0.f, h_state = 0.f;
  float wp = (t < UU) ? Wp[t] : 0.f;
  float bpv = bp[0];
  __syncthreads();

  const __half* zp = zxh + (size_t)b * TT * GG;
  const float* mrow = maskF + b * TT;
  float* outp = out + b * TT;

  for (int step = 0; step < TT; ++step) {
    float zx0 = (float)zp[c0];
    float zx1 = (float)zp[c1];
    float m = mrow[step];
    float a0 = 0.f, a1 = 0.f, a2 = 0.f, a3 = 0.f;
    const uint4* hp4 = (const uint4*)hpk;
#pragma unroll
    for (int p4 = 0; p4 < RP / 4; ++p4) {
      uint4 h4 = hp4[p4];
      a0 = dot2f(h4.x, wA[4 * p4 + 0], a0);
      a1 = dot2f(h4.y, wA[4 * p4 + 1], a1);
      a0 = dot2f(h4.z, wA[4 * p4 + 2], a0);
      a1 = dot2f(h4.w, wA[4 * p4 + 3], a1);
      a2 = dot2f(h4.x, wB[4 * p4 + 0], a2);
      a3 = dot2f(h4.y, wB[4 * p4 + 1], a3);
      a2 = dot2f(h4.z, wB[4 * p4 + 2], a2);
      a3 = dot2f(h4.w, wB[4 * p4 + 3], a3);
    }
#pragma unroll
    for (int s = 0; s < LP / 4; ++s) {
      uint4 h4 = hp4[RP / 4 + s];
      uint4 wa = ldsW4[s * 512 + t];
      uint4 wb = ldsW4[(s + 8) * 512 + t];
      a0 = dot2f(h4.x, wa.x, a0);
      a1 = dot2f(h4.y, wa.y, a1);
      a0 = dot2f(h4.z, wa.z, a0);
      a1 = dot2f(h4.w, wa.w, a1);
      a2 = dot2f(h4.x, wb.x, a2);
      a3 = dot2f(h4.y, wb.y, a3);
      a2 = dot2f(h4.z, wb.z, a2);
      a3 = dot2f(h4.w, wb.w, a3);
    }
    gbuf[c0] = a0 + a1 + zx0;
    gbuf[c1] = a2 + a3 + zx1;
    zp += GG;
    __syncthreads();

    if (t < UU) {
      float gi = gbuf[t];
      float gf = gbuf[t + UU];
      float gg = gbuf[t + 2 * UU];
      float go = gbuf[t + 3 * UU];
      float ig = sigmf_(gi);
      float fg = sigmf_(gf);
      float g_ = tanhf_(gg);
      float og = sigmf_(go);
      float cn = fg * c_state + ig * g_;
      float hn = og * tanhf_(cn);
      bool on = (m > 0.5f);
      c_state = on ? cn : c_state;
      h_state = on ? hn : h_state;
      float hnbr = __shfl_down(h_state, 1);
      if (!(t & 1)) hpk[t >> 1] = packh2(h_state, hnbr);
      float pp = h_state * wp;
#pragma unroll
      for (int off = 32; off > 0; off >>= 1) pp += __shfl_down(pp, off);
      if ((t & 63) == 0) red[t >> 6] = pp;
    }
    __syncthreads();
    if (t == 0) {
      float s = red[0] + red[1] + red[2] + red[3] + bpv;
      outp[step] = 1.f / (1.f + __expf(-s));
    }
  }
}

extern "C" void kernel_launch(void* const* d_in, const int* in_sizes, int n_in,
                              void* d_out, int out_size, void* d_ws, size_t ws_size,
                              hipStream_t stream) {
  const float* x = (const float*)d_in[0];
  const float* Wfc = (const float*)d_in[1];
  const float* bfc = (const float*)d_in[2];
  const float* Wx = (const float*)d_in[3];
  const float* Wh = (const float*)d_in[4];
  const float* blstm = (const float*)d_in[5];
  const float* Wp = (const float*)d_in[6];
  const float* bp = (const float*)d_in[7];
  float* out = (float*)d_out;

  char* ws = (char*)d_ws;
  float* maskF = (float*)(ws);                                      // 128 KB
  __half* zh = (__half*)(ws + 131072);                              // 16.78 MB
  __half* zxh = (__half*)(ws + 131072 + 16777216);                  // 67.1 MB
  uint32_t* whPk = (uint32_t*)(ws + 131072 + 16777216 + 67108864);  // 512 KB

  mask_kernel<<<BB * TT, 256, 0, stream>>>(x, maskF);
  pack_wh<<<512, 256, 0, stream>>>(Wh, whPk);
  gemm16<float, true><<<dim3((BB * TT) / 128, UU / 64), 256, 0, stream>>>(
      x, Wfc, bfc, zh, BB * TT, UU, FF);
  gemm16<__half, false><<<dim3((BB * TT) / 128, GG / 64), 256, 0, stream>>>(
      zh, Wx, blstm, zxh, BB * TT, GG, UU);
  lstm_rec<<<BB, 512, 0, stream>>>(whPk, zxh, maskF, Wp, bp, out);
}